// Round 2
// baseline (197.438 us; speedup 1.0000x reference)
//
#include <hip/hip_runtime.h>

// Fold (col2im 3D): x (1,16,8,8,8,4096) f32 -> out (1,16,68,68,68) f32
// KS=8, ST=4, n=16, H=W=D=68.
// Gather form: o = 4*m + kl, m in [0,17), kl in [0,4);
// out[c,o1,o2,o3] = sum_{kh1,kh2,kh3 in {0,1}^3} x[c, 4*kh1+kl1, 4*kh2+kl2, 4*kh3+kl3,
//                                                  m1-kh1, m2-kh2, m3-kh3]   (bounds-clipped)
// Each input element is read exactly once; each output written exactly once.

#define TOTAL_THREADS (16 * 68 * 68 * 17)  // 1,257,728 -> 4913 blocks of 256

__global__ __launch_bounds__(256) void fold_kernel(const float* __restrict__ x,
                                                   float* __restrict__ out) {
    int t = blockIdx.x * 256 + threadIdx.x;
    // t -> (c, o1, o2, m3), m3 fastest (17 values)
    int m3 = t % 17;
    int r  = t / 17;
    int o2 = r % 68;
    r /= 68;
    int o1 = r % 68;
    int c  = r / 68;

    int m1 = o1 >> 2, kl1 = o1 & 3;
    int m2 = o2 >> 2, kl2 = o2 & 3;

    float acc0 = 0.f, acc1 = 0.f, acc2 = 0.f, acc3 = 0.f;

    // input strides: c: 2^21, k1: 2^18, k2: 2^15, k3: 2^12, n1: 2^8, n2: 2^4, n3: 1
#pragma unroll
    for (int kh1 = 0; kh1 < 2; ++kh1) {
        int n1 = m1 - kh1;
        if ((unsigned)n1 >= 16u) continue;
        int k1 = kl1 + 4 * kh1;
#pragma unroll
        for (int kh2 = 0; kh2 < 2; ++kh2) {
            int n2 = m2 - kh2;
            if ((unsigned)n2 >= 16u) continue;
            int k2 = kl2 + 4 * kh2;
            const float* p = x + ((size_t)c << 21) + ((size_t)k1 << 18)
                               + ((size_t)k2 << 15) + (n1 << 8) + (n2 << 4);
#pragma unroll
            for (int kh3 = 0; kh3 < 2; ++kh3) {
                int n3 = m3 - kh3;
                if ((unsigned)n3 >= 16u) continue;
                const float* q = p + ((size_t)(kh3 * 4) << 12) + n3;
                acc0 += q[0 * 4096];
                acc1 += q[1 * 4096];
                acc2 += q[2 * 4096];
                acc3 += q[3 * 4096];
            }
        }
    }

    size_t oidx = ((((size_t)c * 68) + o1) * 68 + o2) * 68 + (m3 << 2);
    float4 v = make_float4(acc0, acc1, acc2, acc3);
    *reinterpret_cast<float4*>(out + oidx) = v;
}

extern "C" void kernel_launch(void* const* d_in, const int* in_sizes, int n_in,
                              void* d_out, int out_size, void* d_ws, size_t ws_size,
                              hipStream_t stream) {
    const float* x = (const float*)d_in[0];
    float* out = (float*)d_out;
    dim3 grid(TOTAL_THREADS / 256), block(256);
    hipLaunchKernelGGL(fold_kernel, grid, block, 0, stream, x, out);
}

// Round 4
// 194.058 us; speedup vs baseline: 1.0174x; 1.0174x over previous
//
#include <hip/hip_runtime.h>

// Fold (col2im 3D): x (1,16,8,8,8,4096) f32 -> out (1,16,68,68,68) f32
// KS=8, ST=4, n=16, H=W=D=68.
// Bijection per dim: o = 4*m + kl, m in [0,17), kl in [0,4);
//   out[c,o1,o2,o3] = sum over kh in {0,1}^3 of
//     x[c, 4*kh1+kl1, 4*kh2+kl2, 4*kh3+kl3, m1-kh1, m2-kh2, m3-kh3] (bounds-clipped)
//
// Vectorized-gather mapping: thread = (c, o1, o2, kl3, b), b = n3-quad index.
// Thread owns outputs o3 = 16*b + kl3 + 4*i, i=0..3 (m3 = 4b+i), and b==0
// additionally owns m3=16 (o3 = 64+kl3).
// Per (kh1,kh2) combo: two aligned float4 loads cover all 8 contributions:
//   A = x4[k3=kl3,   n3=4b..4b+3]  -> acc_i += A[i]           (kh3=0)
//   B = x4[k3=kl3+4, n3=4b..4b+3]  -> acc_{i} += B[i-1], i>=1 (kh3=1)
//   acc_0 (kh3=1) needs n3=4b-1 = lane(b-1).B[3]  -> __shfl_up(B.w, 1)
//   m3=16 (kh3=1) needs n3=15    = lane(b=3).B[3] -> __shfl_down(B.w, 3)
// 16-lane groups (b,kl3) share (o1,o2) so the bounds mask is group-uniform and
// all shfl sources are active whenever the reader is. Groups never straddle a
// wave (64 % 16 == 0). Every input element is read exactly once; every output
// written exactly once. Load pattern: 4 consecutive b-lanes = one full 64B line.

#define TOTAL_THREADS (16 * 68 * 68 * 16)  // 1,183,744 -> 4624 blocks of 256

__global__ __launch_bounds__(256) void fold_kernel(const float* __restrict__ x,
                                                   float* __restrict__ out) {
    int t = blockIdx.x * 256 + threadIdx.x;
    int b   = t & 3;
    int kl3 = (t >> 2) & 3;
    int r   = t >> 4;
    int o2 = r % 68;
    r /= 68;
    int o1 = r % 68;
    int c  = r / 68;

    int m1 = o1 >> 2, kl1 = o1 & 3;
    int m2 = o2 >> 2, kl2 = o2 & 3;

    float a0 = 0.f, a1 = 0.f, a2 = 0.f, a3 = 0.f, a4 = 0.f;

    // input strides: c 2^21, k1 2^18, k2 2^15, k3 2^12, n1 2^8, n2 2^4, n3 1
#pragma unroll
    for (int kh1 = 0; kh1 < 2; ++kh1) {
        int n1 = m1 - kh1;
        bool v1 = (unsigned)n1 < 16u;
        int k1 = kl1 + 4 * kh1;
#pragma unroll
        for (int kh2 = 0; kh2 < 2; ++kh2) {
            int n2 = m2 - kh2;
            bool ok = v1 && ((unsigned)n2 < 16u);  // uniform per 16-lane group
            int k2 = kl2 + 4 * kh2;

            ptrdiff_t base = ((ptrdiff_t)c << 21) + ((ptrdiff_t)k1 << 18)
                           + ((ptrdiff_t)k2 << 15) + ((ptrdiff_t)n1 << 8)
                           + ((ptrdiff_t)n2 << 4) + 4 * b;

            float4 A = make_float4(0.f, 0.f, 0.f, 0.f);
            float4 B = make_float4(0.f, 0.f, 0.f, 0.f);
            if (ok) {
                A = *reinterpret_cast<const float4*>(x + base + ((ptrdiff_t)kl3 << 12));
                B = *reinterpret_cast<const float4*>(x + base + ((ptrdiff_t)(kl3 + 4) << 12));
            }
            // shfls run unconditionally (wave-uniform control flow here);
            // sources are in the same 16-lane group as readers.
            float s_up = __shfl_up(B.w, 1);    // lane b-1's B.w  (n3 = 4b-1)
            float s_dn = __shfl_down(B.w, 3);  // lane b+3's B.w  (n3 = 15, when b==0)
            if (ok) {
                a0 += A.x;
                a1 += A.y + B.x;
                a2 += A.z + B.y;
                a3 += A.w + B.z;
                if (b > 0) a0 += s_up;
                if (b == 0) a4 += s_dn;
            }
        }
    }

    // out strides: c 68^3, o1 68^2, o2 68, o3 1; this thread's o3 base = 16b+kl3
    size_t ob = ((((size_t)c * 68) + o1) * 68 + o2) * 68 + (size_t)(16 * b + kl3);
    out[ob]      = a0;
    out[ob + 4]  = a1;
    out[ob + 8]  = a2;
    out[ob + 12] = a3;
    if (b == 0) out[ob + 64] = a4;  // m3 = 16 tail
}

extern "C" void kernel_launch(void* const* d_in, const int* in_sizes, int n_in,
                              void* d_out, int out_size, void* d_ws, size_t ws_size,
                              hipStream_t stream) {
    const float* x = (const float*)d_in[0];
    float* out = (float*)d_out;
    dim3 grid(TOTAL_THREADS / 256), block(256);
    hipLaunchKernelGGL(fold_kernel, grid, block, 0, stream, x, out);
}